// Round 14
// baseline (91.218 us; speedup 1.0000x reference)
//
#include <hip/hip_runtime.h>
#include <hip/hip_bf16.h>

typedef unsigned short u16;
typedef unsigned int u32;
typedef __attribute__((ext_vector_type(8))) short short8;
typedef __attribute__((ext_vector_type(16))) float f32x16;

#define SEQ 2048

__device__ __forceinline__ u16 f2bf(float f) {
  union { __hip_bfloat16 h; u16 u; } c;
  c.h = __float2bfloat16(f);
  return c.u;
}

__device__ __forceinline__ float exp2fast(float x) {
  return __builtin_amdgcn_exp2f(x);  // v_exp_f32 (base-2)
}

// ---------------- prep: transpose+scale Q,K -> ws [bh][seq][64] bf16 ----------------
// scale = 64^-0.25 * sqrt(log2 e)  (exp2-domain softmax)
__global__ __launch_bounds__(256) void prep_qk(const float* __restrict__ qkv,
                                               u16* __restrict__ wsQ,
                                               u16* __restrict__ wsK) {
  __shared__ float tile[64 * 67];
  const int tid = threadIdx.x;
  const int t0 = blockIdx.x * 64;
  const int bh = blockIdx.y;
  const int b = bh >> 3, h = bh & 7;
  const int isK = blockIdx.z;
  const float scale = 0.42466090014692505f;
  const size_t inbase = ((size_t)b * 1536 + (size_t)isK * 512 + (size_t)h * 64) * SEQ;

  const int c = tid >> 2, tq = tid & 3;
#pragma unroll
  for (int u = 0; u < 4; ++u) {
    const int t = tq * 16 + u * 4;
    const float4 v = *(const float4*)(qkv + inbase + (size_t)c * SEQ + t0 + t);
    tile[c * 67 + t + 0] = v.x * scale;
    tile[c * 67 + t + 1] = v.y * scale;
    tile[c * 67 + t + 2] = v.z * scale;
    tile[c * 67 + t + 3] = v.w * scale;
  }
  __syncthreads();
  const int tt = tid >> 2, cq = tid & 3, c0 = cq * 16;
  u16* dst = (isK ? wsK : wsQ) + ((size_t)bh * SEQ + t0 + tt) * 64 + c0;
  union { u16 us[8]; uint4 v; } p0, p1;
#pragma unroll
  for (int i = 0; i < 8; ++i) p0.us[i] = f2bf(tile[(c0 + i) * 67 + tt]);
#pragma unroll
  for (int i = 0; i < 8; ++i) p1.us[i] = f2bf(tile[(c0 + 8 + i) * 67 + tt]);
  *(uint4*)(dst) = p0.v;
  *(uint4*)(dst + 8) = p1.v;
}

// ---------------- prep: V -> fragment-linear V'[bh][sb32][ct*2+ks2][lane][8] ----------------
// lane=hi*32+tl holds V[c=ct*32+tl][s=sb32*32+ks2*16+hi*8 .. +7]; writes fully coalesced.
__global__ __launch_bounds__(256) void prep_v(const float* __restrict__ qkv,
                                              u16* __restrict__ wsV) {
  const int idx = blockIdx.x * 256 + threadIdx.x;  // 0..524287 == V' uint4 index
  const int slot = idx & 255;
  const int sb32 = (idx >> 8) & 63;
  const int bh = idx >> 14;
  const int lane = slot & 63;
  const int ctks = slot >> 6;
  const int ct = ctks >> 1, ks2 = ctks & 1;
  const int hi = lane >> 5, tl = lane & 31;
  const int cc = ct * 32 + tl;
  const int s = sb32 * 32 + ks2 * 16 + hi * 8;
  const int b = bh >> 3, h = bh & 7;
  const float* src = qkv + ((size_t)b * 1536 + 1024 + (size_t)h * 64 + cc) * SEQ + s;
  const float4 v0 = *(const float4*)(src);
  const float4 v1 = *(const float4*)(src + 4);
  union { u16 us[8]; uint4 q; } pk;
  pk.us[0] = f2bf(v0.x); pk.us[1] = f2bf(v0.y); pk.us[2] = f2bf(v0.z); pk.us[3] = f2bf(v0.w);
  pk.us[4] = f2bf(v1.x); pk.us[5] = f2bf(v1.y); pk.us[6] = f2bf(v1.z); pk.us[7] = f2bf(v1.w);
  *(uint4*)(wsV + (size_t)idx * 8) = pk.q;
}

// ---------------- fused flash attention ----------------
// 256 thr = 4 waves = 2 s-half streams x 2 t-units; wave: QBLK=64 t, 1024 s.
// K staged in LDS (8KB/stream/iter, XOR-swizzled, double-buffered, stream-amortized,
// load-early/write-late, 1 barrier/iter over only 4 waves). V fragments DIRECT from
// fragment-linear V'. Fixed-m exp2 softmax. grid 512 (XCD-swizzled, 4 bh/XCD) ->
// 2 INDEPENDENT blocks/CU: one computes while the other drains its barrier.
__global__ __launch_bounds__(256) void attn_kernel(const u16* __restrict__ wsQ,
                                                   const u16* __restrict__ wsK,
                                                   const u16* __restrict__ wsV,
                                                   float* __restrict__ out) {
  // main loop: stream sh owns [sh*16384, +16KB) = 2 x 8KB K double-buffer.
  // epilogue: reused as 2 x 16KB float partial slots (one per t-unit).
  __shared__ __align__(16) char smem[32768];
  __shared__ float Xl[2][2][32];  // [unit][cb][tl]

  const int tid = threadIdx.x;
  const int w = tid >> 6;
  const int lane = tid & 63;
  const int tl = lane & 31;
  const int hi = lane >> 5;
  const int sh = w >> 1;    // s-half stream
  const int u = w & 1;      // t-unit within block
  const int ts = tid & 127; // thread id within stream

  const int bid = blockIdx.x;
  const int vb = (bid & 7) * 64 + (bid >> 3);  // XCD swizzle: 4 bh per XCD
  const int tbp = vb & 15, bh = vb >> 4;
  const int tq0 = tbp * 128 + u * 64;

  const u16* qb = wsQ + (size_t)bh * (SEQ * 64);
  const u16* kb = wsK + (size_t)bh * (SEQ * 64);
  const u16* vstream = wsV + (size_t)bh * 131072 + lane * 8;

  char* Kbuf = smem + sh * 16384;

  // Q fragments: qf[cb][ks] = Q[t=tq0+cb*32+tl][c=16ks+8hi .. +7]
  short8 qf[2][4];
#pragma unroll
  for (int cb = 0; cb < 2; ++cb) {
    const u16* qrow = qb + (size_t)(tq0 + cb * 32 + tl) * 64 + 8 * hi;
#pragma unroll
    for (int ks = 0; ks < 4; ++ks) qf[cb][ks] = *(const short8*)(qrow + 16 * ks);
  }

  f32x16 acc[4];  // [cb*2+ct]
#pragma unroll
  for (int a = 0; a < 4; ++a)
#pragma unroll
    for (int r = 0; r < 16; ++r) acc[a][r] = 0.0f;
  float la0[4] = {0, 0, 0, 0};
  float la1[4] = {0, 0, 0, 0};

  uint4 kg[4];

#define STAGE_LOAD(S)                                                       \
  do {                                                                      \
    _Pragma("unroll")                                                       \
    for (int _it = 0; _it < 4; ++_it) {                                     \
      const int _idx = _it * 128 + ts;                                      \
      const int _row = _idx >> 3, _g = _idx & 7;                            \
      kg[_it] = *(const uint4*)(kb + (size_t)((S) + _row) * 64 + _g * 8);   \
    }                                                                       \
  } while (0)

#define STAGE_WRITE(PBUF)                                                   \
  do {                                                                      \
    char* _kd = Kbuf + (PBUF) * 8192;                                       \
    _Pragma("unroll")                                                       \
    for (int _it = 0; _it < 4; ++_it) {                                     \
      const int _idx = _it * 128 + ts;                                      \
      const int _row = _idx >> 3, _g = _idx & 7;                            \
      *(uint4*)(_kd + _row * 128 + ((_g ^ (_row & 7)) << 4)) = kg[_it];     \
    }                                                                       \
  } while (0)

#define PACK_P(PV16, PF0, PF1)                                                        \
  do {                                                                                \
    u32 _pk[8];                                                                       \
    _Pragma("unroll")                                                                 \
    for (int _q = 0; _q < 8; ++_q) {                                                  \
      const float _lo = PV16[2 * _q], _hi = PV16[2 * _q + 1];                         \
      asm("v_cvt_pk_bf16_f32 %0, %1, %2" : "=v"(_pk[_q]) : "v"(_lo), "v"(_hi));       \
    }                                                                                 \
    asm("v_permlane32_swap_b32 %0, %1" : "+v"(_pk[0]), "+v"(_pk[2]));                 \
    asm("v_permlane32_swap_b32 %0, %1" : "+v"(_pk[1]), "+v"(_pk[3]));                 \
    asm("v_permlane32_swap_b32 %0, %1" : "+v"(_pk[4]), "+v"(_pk[6]));                 \
    asm("v_permlane32_swap_b32 %0, %1" : "+v"(_pk[5]), "+v"(_pk[7]));                 \
    union { u32 u[4]; short8 v; } _f0, _f1;                                           \
    _f0.u[0] = _pk[0]; _f0.u[1] = _pk[1]; _f0.u[2] = _pk[2]; _f0.u[3] = _pk[3];       \
    _f1.u[0] = _pk[4]; _f1.u[1] = _pk[5]; _f1.u[2] = _pk[6]; _f1.u[3] = _pk[7];       \
    PF0 = _f0.v; PF1 = _f1.v;                                                         \
  } while (0)

  // prologue: stage tile 0 into buf 0
  STAGE_LOAD(sh * 1024);
  STAGE_WRITE(0);
  __syncthreads();

  for (int i = 0; i < 16; ++i) {
    if (i < 15) STAGE_LOAD(sh * 1024 + (i + 1) * 64);  // T14: load-early

    const char* Ks = Kbuf + (i & 1) * 8192;
    const int jbase = sh * 32 + i * 2;

#pragma unroll
    for (int ss = 0; ss < 2; ++ss) {
      const int krow = ss * 32 + tl;
      short8 kf[4];
#pragma unroll
      for (int ks = 0; ks < 4; ++ks)
        kf[ks] = *(const short8*)(Ks + krow * 128 + (((2 * ks + hi) ^ (krow & 7)) << 4));

      f32x16 s0 = {0, 0, 0, 0, 0, 0, 0, 0, 0, 0, 0, 0, 0, 0, 0, 0};
      f32x16 s1 = s0;
      __builtin_amdgcn_s_setprio(1);
#pragma unroll
      for (int ks = 0; ks < 4; ++ks) {
        s0 = __builtin_amdgcn_mfma_f32_32x32x16_bf16(kf[ks], qf[0][ks], s0, 0, 0, 0);
        s1 = __builtin_amdgcn_mfma_f32_32x32x16_bf16(kf[ks], qf[1][ks], s1, 0, 0, 0);
      }
      __builtin_amdgcn_s_setprio(0);

      // V fragments direct from fragment-linear V' (coalesced); consumed after softmax
      const u16* vp = vstream + (size_t)(jbase + ss) * 2048;
      const short8 vf0 = *(const short8*)(vp);
      const short8 vf1 = *(const short8*)(vp + 512);
      const short8 vf2 = *(const short8*)(vp + 1024);
      const short8 vf3 = *(const short8*)(vp + 1536);

#pragma unroll
      for (int r = 0; r < 16; ++r) s0[r] = exp2fast(s0[r]);
#pragma unroll
      for (int r = 0; r < 16; ++r) s1[r] = exp2fast(s1[r]);
#pragma unroll
      for (int j = 0; j < 4; ++j) {
        la0[j] += (s0[4 * j] + s0[4 * j + 1]) + (s0[4 * j + 2] + s0[4 * j + 3]);
        la1[j] += (s1[4 * j] + s1[4 * j + 1]) + (s1[4 * j + 2] + s1[4 * j + 3]);
      }

      short8 pf00, pf01, pf10, pf11;
      PACK_P(s0, pf00, pf01);
      PACK_P(s1, pf10, pf11);

      __builtin_amdgcn_s_setprio(1);
      acc[0] = __builtin_amdgcn_mfma_f32_32x32x16_bf16(vf0, pf00, acc[0], 0, 0, 0);
      acc[0] = __builtin_amdgcn_mfma_f32_32x32x16_bf16(vf1, pf01, acc[0], 0, 0, 0);
      acc[1] = __builtin_amdgcn_mfma_f32_32x32x16_bf16(vf2, pf00, acc[1], 0, 0, 0);
      acc[1] = __builtin_amdgcn_mfma_f32_32x32x16_bf16(vf3, pf01, acc[1], 0, 0, 0);
      acc[2] = __builtin_amdgcn_mfma_f32_32x32x16_bf16(vf0, pf10, acc[2], 0, 0, 0);
      acc[2] = __builtin_amdgcn_mfma_f32_32x32x16_bf16(vf1, pf11, acc[2], 0, 0, 0);
      acc[3] = __builtin_amdgcn_mfma_f32_32x32x16_bf16(vf2, pf10, acc[3], 0, 0, 0);
      acc[3] = __builtin_amdgcn_mfma_f32_32x32x16_bf16(vf3, pf11, acc[3], 0, 0, 0);
      __builtin_amdgcn_s_setprio(0);
    }

    if (i < 15) STAGE_WRITE((i + 1) & 1);  // write-late into the other buffer
    __syncthreads();
  }

  // ---- epilogue: reduce l, 2-stream merge (fixed m => plain sums), store ----
  float l0 = (la0[0] + la0[1]) + (la0[2] + la0[3]);
  float l1 = (la1[0] + la1[1]) + (la1[2] + la1[3]);
  l0 += __shfl_xor(l0, 32, 64);
  l1 += __shfl_xor(l1, 32, 64);

  float* Xa = (float*)smem + u * 4096;
  if (sh == 1) {
#pragma unroll
    for (int a = 0; a < 4; ++a)
#pragma unroll
      for (int r = 0; r < 16; ++r) Xa[(a * 16 + r) * 64 + lane] = acc[a][r];
    Xl[u][0][tl] = l0;
    Xl[u][1][tl] = l1;
  }
  __syncthreads();
  if (sh == 0) {
    float* ob = out + (size_t)bh * 64 * SEQ;
    const float inv0 = 1.0f / (l0 + Xl[u][0][tl]);
    const float inv1 = 1.0f / (l1 + Xl[u][1][tl]);
#pragma unroll
    for (int r = 0; r < 16; ++r) {
      const int c0 = (r & 3) + 8 * (r >> 2) + 4 * hi;
      const int ta = tq0 + tl, tb2 = tq0 + 32 + tl;
      ob[(size_t)c0 * SEQ + ta] = (acc[0][r] + Xa[(0 * 16 + r) * 64 + lane]) * inv0;
      ob[(size_t)(c0 + 32) * SEQ + ta] = (acc[1][r] + Xa[(1 * 16 + r) * 64 + lane]) * inv0;
      ob[(size_t)c0 * SEQ + tb2] = (acc[2][r] + Xa[(2 * 16 + r) * 64 + lane]) * inv1;
      ob[(size_t)(c0 + 32) * SEQ + tb2] = (acc[3][r] + Xa[(3 * 16 + r) * 64 + lane]) * inv1;
    }
  }
}

extern "C" void kernel_launch(void* const* d_in, const int* in_sizes, int n_in,
                              void* d_out, int out_size, void* d_ws, size_t ws_size,
                              hipStream_t stream) {
  const float* qkv = (const float*)d_in[0];
  float* out = (float*)d_out;
  u16* wsQ = (u16*)d_ws;
  u16* wsK = wsQ + (size_t)32 * SEQ * 64;
  u16* wsV = wsK + (size_t)32 * SEQ * 64;

  prep_qk<<<dim3(32, 32, 2), 256, 0, stream>>>(qkv, wsQ, wsK);
  prep_v<<<2048, 256, 0, stream>>>(qkv, wsV);
  attn_kernel<<<512, 256, 0, stream>>>(wsQ, wsK, wsV, out);
}

// Round 15
// 87.553 us; speedup vs baseline: 1.0419x; 1.0419x over previous
//
#include <hip/hip_runtime.h>
#include <hip/hip_bf16.h>

typedef unsigned short u16;
typedef unsigned int u32;
typedef __attribute__((ext_vector_type(8))) short short8;
typedef __attribute__((ext_vector_type(16))) float f32x16;

#define SEQ 2048

__device__ __forceinline__ u16 f2bf(float f) {
  union { __hip_bfloat16 h; u16 u; } c;
  c.h = __float2bfloat16(f);
  return c.u;
}

__device__ __forceinline__ float exp2fast(float x) {
  return __builtin_amdgcn_exp2f(x);  // v_exp_f32 (base-2)
}

// ---------------- prep: transpose+scale Q,K -> ws [bh][seq][64] bf16 ----------------
// scale = 64^-0.25 * sqrt(log2 e)  (exp2-domain softmax)
__global__ __launch_bounds__(256) void prep_qk(const float* __restrict__ qkv,
                                               u16* __restrict__ wsQ,
                                               u16* __restrict__ wsK) {
  __shared__ float tile[64 * 67];
  const int tid = threadIdx.x;
  const int t0 = blockIdx.x * 64;
  const int bh = blockIdx.y;
  const int b = bh >> 3, h = bh & 7;
  const int isK = blockIdx.z;
  const float scale = 0.42466090014692505f;
  const size_t inbase = ((size_t)b * 1536 + (size_t)isK * 512 + (size_t)h * 64) * SEQ;

  const int c = tid >> 2, tq = tid & 3;
#pragma unroll
  for (int u = 0; u < 4; ++u) {
    const int t = tq * 16 + u * 4;
    const float4 v = *(const float4*)(qkv + inbase + (size_t)c * SEQ + t0 + t);
    tile[c * 67 + t + 0] = v.x * scale;
    tile[c * 67 + t + 1] = v.y * scale;
    tile[c * 67 + t + 2] = v.z * scale;
    tile[c * 67 + t + 3] = v.w * scale;
  }
  __syncthreads();
  const int tt = tid >> 2, cq = tid & 3, c0 = cq * 16;
  u16* dst = (isK ? wsK : wsQ) + ((size_t)bh * SEQ + t0 + tt) * 64 + c0;
  union { u16 us[8]; uint4 v; } p0, p1;
#pragma unroll
  for (int i = 0; i < 8; ++i) p0.us[i] = f2bf(tile[(c0 + i) * 67 + tt]);
#pragma unroll
  for (int i = 0; i < 8; ++i) p1.us[i] = f2bf(tile[(c0 + 8 + i) * 67 + tt]);
  *(uint4*)(dst) = p0.v;
  *(uint4*)(dst + 8) = p1.v;
}

// ---------------- prep: V -> fragment-linear V'[bh][sb32][ct*2+ks2][lane][8] ----------------
// lane=hi*32+tl holds V[c=ct*32+tl][s=sb32*32+ks2*16+hi*8 .. +7]; writes fully coalesced.
__global__ __launch_bounds__(256) void prep_v(const float* __restrict__ qkv,
                                              u16* __restrict__ wsV) {
  const int idx = blockIdx.x * 256 + threadIdx.x;  // 0..524287 == V' uint4 index
  const int slot = idx & 255;
  const int sb32 = (idx >> 8) & 63;
  const int bh = idx >> 14;
  const int lane = slot & 63;
  const int ctks = slot >> 6;
  const int ct = ctks >> 1, ks2 = ctks & 1;
  const int hi = lane >> 5, tl = lane & 31;
  const int cc = ct * 32 + tl;
  const int s = sb32 * 32 + ks2 * 16 + hi * 8;
  const int b = bh >> 3, h = bh & 7;
  const float* src = qkv + ((size_t)b * 1536 + 1024 + (size_t)h * 64 + cc) * SEQ + s;
  const float4 v0 = *(const float4*)(src);
  const float4 v1 = *(const float4*)(src + 4);
  union { u16 us[8]; uint4 q; } pk;
  pk.us[0] = f2bf(v0.x); pk.us[1] = f2bf(v0.y); pk.us[2] = f2bf(v0.z); pk.us[3] = f2bf(v0.w);
  pk.us[4] = f2bf(v1.x); pk.us[5] = f2bf(v1.y); pk.us[6] = f2bf(v1.z); pk.us[7] = f2bf(v1.w);
  *(uint4*)(wsV + (size_t)idx * 8) = pk.q;
}

// ---------------- fused flash attention (R13 structure, BK=128: half the barriers) ----------------
// 512 thr = 8 waves = 2 s-half streams x 4 t-units. Wave: QBLK=64 t, 1024 s.
// K staged in LDS (16KB/stream/iter = 128 s, XOR-swizzled, double-buffered, block-amortized,
// load-early/write-late, 1 barrier per 128 s -> 8 barriers total). V fragments DIRECT from
// fragment-linear V' (coalesced 1KB wave-loads, issued post-QK, consumed post-softmax).
// Fixed-m softmax (p = exp2(S), |S| <~ 9 here); final /l = exact softmax.
// grid 256 (XCD-swizzled: 4 bh per XCD).
__global__ __launch_bounds__(512) void attn_kernel(const u16* __restrict__ wsQ,
                                                   const u16* __restrict__ wsK,
                                                   const u16* __restrict__ wsV,
                                                   float* __restrict__ out) {
  // main loop: stream sh owns [sh*32768, +32KB) = 2 x 16KB K double-buffer.
  // epilogue: reused as 4 x 16KB float partial slots.
  __shared__ __align__(16) char smem[65536];
  __shared__ float Xl[4][2][32];  // [unit][cb][tl]

  const int tid = threadIdx.x;
  const int w = tid >> 6;
  const int lane = tid & 63;
  const int tl = lane & 31;
  const int hi = lane >> 5;
  const int sh = w >> 2;    // s-half stream
  const int u = w & 3;      // t-unit within block
  const int ts = tid & 255; // thread id within stream

  const int bid = blockIdx.x;
  const int vb = (bid & 7) * 32 + (bid >> 3);  // XCD swizzle: 4 bh per XCD
  const int tblk = vb & 7, bh = vb >> 3;
  const int tq0 = tblk * 256 + u * 64;

  const u16* qb = wsQ + (size_t)bh * (SEQ * 64);
  const u16* kb = wsK + (size_t)bh * (SEQ * 64);
  const u16* vstream = wsV + (size_t)bh * 131072 + lane * 8;

  char* Kbuf = smem + sh * 32768;

  // Q fragments: qf[cb][ks] = Q[t=tq0+cb*32+tl][c=16ks+8hi .. +7]
  short8 qf[2][4];
#pragma unroll
  for (int cb = 0; cb < 2; ++cb) {
    const u16* qrow = qb + (size_t)(tq0 + cb * 32 + tl) * 64 + 8 * hi;
#pragma unroll
    for (int ks = 0; ks < 4; ++ks) qf[cb][ks] = *(const short8*)(qrow + 16 * ks);
  }

  f32x16 acc[4];  // [cb*2+ct]
#pragma unroll
  for (int a = 0; a < 4; ++a)
#pragma unroll
    for (int r = 0; r < 16; ++r) acc[a][r] = 0.0f;
  float la0[4] = {0, 0, 0, 0};
  float la1[4] = {0, 0, 0, 0};

  uint4 kg[4];

#define STAGE_LOAD(S)                                                       \
  do {                                                                      \
    _Pragma("unroll")                                                       \
    for (int _it = 0; _it < 4; ++_it) {                                     \
      const int _idx = _it * 256 + ts;                                      \
      const int _row = _idx >> 3, _g = _idx & 7;                            \
      kg[_it] = *(const uint4*)(kb + (size_t)((S) + _row) * 64 + _g * 8);   \
    }                                                                       \
  } while (0)

#define STAGE_WRITE(PBUF)                                                   \
  do {                                                                      \
    char* _kd = Kbuf + (PBUF) * 16384;                                      \
    _Pragma("unroll")                                                       \
    for (int _it = 0; _it < 4; ++_it) {                                     \
      const int _idx = _it * 256 + ts;                                      \
      const int _row = _idx >> 3, _g = _idx & 7;                            \
      *(uint4*)(_kd + _row * 128 + ((_g ^ (_row & 7)) << 4)) = kg[_it];     \
    }                                                                       \
  } while (0)

#define PACK_P(PV16, PF0, PF1)                                                        \
  do {                                                                                \
    u32 _pk[8];                                                                       \
    _Pragma("unroll")                                                                 \
    for (int _q = 0; _q < 8; ++_q) {                                                  \
      const float _lo = PV16[2 * _q], _hi = PV16[2 * _q + 1];                         \
      asm("v_cvt_pk_bf16_f32 %0, %1, %2" : "=v"(_pk[_q]) : "v"(_lo), "v"(_hi));       \
    }                                                                                 \
    asm("v_permlane32_swap_b32 %0, %1" : "+v"(_pk[0]), "+v"(_pk[2]));                 \
    asm("v_permlane32_swap_b32 %0, %1" : "+v"(_pk[1]), "+v"(_pk[3]));                 \
    asm("v_permlane32_swap_b32 %0, %1" : "+v"(_pk[4]), "+v"(_pk[6]));                 \
    asm("v_permlane32_swap_b32 %0, %1" : "+v"(_pk[5]), "+v"(_pk[7]));                 \
    union { u32 u[4]; short8 v; } _f0, _f1;                                           \
    _f0.u[0] = _pk[0]; _f0.u[1] = _pk[1]; _f0.u[2] = _pk[2]; _f0.u[3] = _pk[3];       \
    _f1.u[0] = _pk[4]; _f1.u[1] = _pk[5]; _f1.u[2] = _pk[6]; _f1.u[3] = _pk[7];       \
    PF0 = _f0.v; PF1 = _f1.v;                                                         \
  } while (0)

  // prologue: stage tile 0 into buf 0
  STAGE_LOAD(sh * 1024);
  STAGE_WRITE(0);
  __syncthreads();

  for (int i = 0; i < 8; ++i) {
    if (i < 7) STAGE_LOAD(sh * 1024 + (i + 1) * 128);  // T14: load-early

    const char* Ks = Kbuf + (i & 1) * 16384;
    const int jbase = sh * 32 + i * 4;

#pragma unroll
    for (int ss = 0; ss < 4; ++ss) {
      const int krow = ss * 32;
      short8 kf[4];
#pragma unroll
      for (int ks = 0; ks < 4; ++ks)
        kf[ks] = *(const short8*)(Ks + (krow + tl) * 128 + (((2 * ks + hi) ^ ((krow + tl) & 7)) << 4));

      f32x16 s0 = {0, 0, 0, 0, 0, 0, 0, 0, 0, 0, 0, 0, 0, 0, 0, 0};
      f32x16 s1 = s0;
      __builtin_amdgcn_s_setprio(1);
#pragma unroll
      for (int ks = 0; ks < 4; ++ks) {
        s0 = __builtin_amdgcn_mfma_f32_32x32x16_bf16(kf[ks], qf[0][ks], s0, 0, 0, 0);
        s1 = __builtin_amdgcn_mfma_f32_32x32x16_bf16(kf[ks], qf[1][ks], s1, 0, 0, 0);
      }
      __builtin_amdgcn_s_setprio(0);

      // V fragments direct from fragment-linear V' (coalesced); consumed after softmax
      const u16* vp = vstream + (size_t)(jbase + ss) * 2048;
      const short8 vf0 = *(const short8*)(vp);
      const short8 vf1 = *(const short8*)(vp + 512);
      const short8 vf2 = *(const short8*)(vp + 1024);
      const short8 vf3 = *(const short8*)(vp + 1536);

#pragma unroll
      for (int r = 0; r < 16; ++r) s0[r] = exp2fast(s0[r]);
#pragma unroll
      for (int r = 0; r < 16; ++r) s1[r] = exp2fast(s1[r]);
#pragma unroll
      for (int j = 0; j < 4; ++j) {
        la0[j] += (s0[4 * j] + s0[4 * j + 1]) + (s0[4 * j + 2] + s0[4 * j + 3]);
        la1[j] += (s1[4 * j] + s1[4 * j + 1]) + (s1[4 * j + 2] + s1[4 * j + 3]);
      }

      short8 pf00, pf01, pf10, pf11;
      PACK_P(s0, pf00, pf01);
      PACK_P(s1, pf10, pf11);

      __builtin_amdgcn_s_setprio(1);
      acc[0] = __builtin_amdgcn_mfma_f32_32x32x16_bf16(vf0, pf00, acc[0], 0, 0, 0);
      acc[0] = __builtin_amdgcn_mfma_f32_32x32x16_bf16(vf1, pf01, acc[0], 0, 0, 0);
      acc[1] = __builtin_amdgcn_mfma_f32_32x32x16_bf16(vf2, pf00, acc[1], 0, 0, 0);
      acc[1] = __builtin_amdgcn_mfma_f32_32x32x16_bf16(vf3, pf01, acc[1], 0, 0, 0);
      acc[2] = __builtin_amdgcn_mfma_f32_32x32x16_bf16(vf0, pf10, acc[2], 0, 0, 0);
      acc[2] = __builtin_amdgcn_mfma_f32_32x32x16_bf16(vf1, pf11, acc[2], 0, 0, 0);
      acc[3] = __builtin_amdgcn_mfma_f32_32x32x16_bf16(vf2, pf10, acc[3], 0, 0, 0);
      acc[3] = __builtin_amdgcn_mfma_f32_32x32x16_bf16(vf3, pf11, acc[3], 0, 0, 0);
      __builtin_amdgcn_s_setprio(0);
    }

    if (i < 7) STAGE_WRITE((i + 1) & 1);  // write-late into the other buffer
    __syncthreads();
  }

  // ---- epilogue: reduce l, 2-stream merge (fixed m => plain sums), store ----
  float l0 = (la0[0] + la0[1]) + (la0[2] + la0[3]);
  float l1 = (la1[0] + la1[1]) + (la1[2] + la1[3]);
  l0 += __shfl_xor(l0, 32, 64);
  l1 += __shfl_xor(l1, 32, 64);

  float* Xa = (float*)smem + u * 4096;
  if (sh == 1) {
#pragma unroll
    for (int a = 0; a < 4; ++a)
#pragma unroll
      for (int r = 0; r < 16; ++r) Xa[(a * 16 + r) * 64 + lane] = acc[a][r];
    Xl[u][0][tl] = l0;
    Xl[u][1][tl] = l1;
  }
  __syncthreads();
  if (sh == 0) {
    float* ob = out + (size_t)bh * 64 * SEQ;
    const float inv0 = 1.0f / (l0 + Xl[u][0][tl]);
    const float inv1 = 1.0f / (l1 + Xl[u][1][tl]);
#pragma unroll
    for (int r = 0; r < 16; ++r) {
      const int c0 = (r & 3) + 8 * (r >> 2) + 4 * hi;
      const int ta = tq0 + tl, tb2 = tq0 + 32 + tl;
      ob[(size_t)c0 * SEQ + ta] = (acc[0][r] + Xa[(0 * 16 + r) * 64 + lane]) * inv0;
      ob[(size_t)(c0 + 32) * SEQ + ta] = (acc[1][r] + Xa[(1 * 16 + r) * 64 + lane]) * inv0;
      ob[(size_t)c0 * SEQ + tb2] = (acc[2][r] + Xa[(2 * 16 + r) * 64 + lane]) * inv1;
      ob[(size_t)(c0 + 32) * SEQ + tb2] = (acc[3][r] + Xa[(3 * 16 + r) * 64 + lane]) * inv1;
    }
  }
}

extern "C" void kernel_launch(void* const* d_in, const int* in_sizes, int n_in,
                              void* d_out, int out_size, void* d_ws, size_t ws_size,
                              hipStream_t stream) {
  const float* qkv = (const float*)d_in[0];
  float* out = (float*)d_out;
  u16* wsQ = (u16*)d_ws;
  u16* wsK = wsQ + (size_t)32 * SEQ * 64;
  u16* wsV = wsK + (size_t)32 * SEQ * 64;

  prep_qk<<<dim3(32, 32, 2), 256, 0, stream>>>(qkv, wsQ, wsK);
  prep_v<<<2048, 256, 0, stream>>>(qkv, wsV);
  attn_kernel<<<256, 512, 0, stream>>>(wsQ, wsK, wsV, out);
}

// Round 16
// 55.678 us; speedup vs baseline: 1.6383x; 1.5725x over previous
//
#include <hip/hip_runtime.h>
#include <hip/hip_bf16.h>

typedef unsigned short u16;
typedef unsigned int u32;
typedef __attribute__((ext_vector_type(8))) short short8;
typedef __attribute__((ext_vector_type(16))) float f32x16;

#define SEQ 2048

__device__ __forceinline__ u16 f2bf(float f) {
  union { __hip_bfloat16 h; u16 u; } c;
  c.h = __float2bfloat16(f);
  return c.u;
}

__device__ __forceinline__ float exp2fast(float x) {
  return __builtin_amdgcn_exp2f(x);  // v_exp_f32 (base-2)
}

// ---------------- fused prep ----------------
// z=0: Q -> ws [bh][seq][64] row-major (scaled).  z=1: K -> same (scaled).
// z=2: V -> fragment-linear V'[bh][sb32][ct*2+ks2][lane][8] (2 sb32-tiles per block).
// scale = 64^-0.25 * sqrt(log2 e)  (exp2-domain softmax)
__global__ __launch_bounds__(256) void prep_all(const float* __restrict__ qkv,
                                                u16* __restrict__ wsQ,
                                                u16* __restrict__ wsK,
                                                u16* __restrict__ wsV) {
  const int tid = threadIdx.x;
  const int bh = blockIdx.y;
  const int b = bh >> 3, h = bh & 7;
  const int z = blockIdx.z;

  if (z == 2) {
    // V-prep: block x covers tiles j = 2x, 2x+1
#pragma unroll
    for (int rep = 0; rep < 2; ++rep) {
      const int il = rep * 256 + tid;           // 0..511
      const int j = 2 * blockIdx.x + (il >> 8); // sb32 tile
      const int slot = il & 255;
      const int lane = slot & 63;
      const int ctks = slot >> 6;
      const int ct = ctks >> 1, ks2 = ctks & 1;
      const int hi = lane >> 5, tl = lane & 31;
      const int cc = ct * 32 + tl;
      const int s = j * 32 + ks2 * 16 + hi * 8;
      const float* src = qkv + ((size_t)b * 1536 + 1024 + (size_t)h * 64 + cc) * SEQ + s;
      const float4 v0 = *(const float4*)(src);
      const float4 v1 = *(const float4*)(src + 4);
      union { u16 us[8]; uint4 q; } pk;
      pk.us[0] = f2bf(v0.x); pk.us[1] = f2bf(v0.y); pk.us[2] = f2bf(v0.z); pk.us[3] = f2bf(v0.w);
      pk.us[4] = f2bf(v1.x); pk.us[5] = f2bf(v1.y); pk.us[6] = f2bf(v1.z); pk.us[7] = f2bf(v1.w);
      *(uint4*)(wsV + ((size_t)bh * 16384 + (size_t)j * 256 + slot) * 8) = pk.q;
    }
    return;
  }

  __shared__ float tile[64 * 67];
  const int t0 = blockIdx.x * 64;
  const int isK = z;
  const float scale = 0.42466090014692505f;
  const size_t inbase = ((size_t)b * 1536 + (size_t)isK * 512 + (size_t)h * 64) * SEQ;

  const int c = tid >> 2, tq = tid & 3;
#pragma unroll
  for (int u = 0; u < 4; ++u) {
    const int t = tq * 16 + u * 4;
    const float4 v = *(const float4*)(qkv + inbase + (size_t)c * SEQ + t0 + t);
    tile[c * 67 + t + 0] = v.x * scale;
    tile[c * 67 + t + 1] = v.y * scale;
    tile[c * 67 + t + 2] = v.z * scale;
    tile[c * 67 + t + 3] = v.w * scale;
  }
  __syncthreads();
  const int tt = tid >> 2, cq = tid & 3, c0 = cq * 16;
  u16* dst = (isK ? wsK : wsQ) + ((size_t)bh * SEQ + t0 + tt) * 64 + c0;
  union { u16 us[8]; uint4 v; } p0, p1;
#pragma unroll
  for (int i = 0; i < 8; ++i) p0.us[i] = f2bf(tile[(c0 + i) * 67 + tt]);
#pragma unroll
  for (int i = 0; i < 8; ++i) p1.us[i] = f2bf(tile[(c0 + 8 + i) * 67 + tt]);
  *(uint4*)(dst) = p0.v;
  *(uint4*)(dst + 8) = p1.v;
}

// ---------------- fused flash attention (R13 structure + mid-iter STAGE_WRITE) ----------------
// 512 thr = 8 waves = 2 s-half streams x 4 t-units. Wave: QBLK=64 t, 1024 s.
// K staged in LDS (8KB/stream/iter, XOR-swizzled, double-buffered, block-amortized,
// load-early / write-mid (covered by ss=1 compute), 1 barrier/iter). V fragments DIRECT
// from fragment-linear V'. Fixed-m softmax (p = exp2(S)); final /l = exact softmax.
// grid 256 (XCD-swizzled: 4 bh per XCD).
__global__ __launch_bounds__(512) void attn_kernel(const u16* __restrict__ wsQ,
                                                   const u16* __restrict__ wsK,
                                                   const u16* __restrict__ wsV,
                                                   float* __restrict__ out) {
  // main loop: stream sh owns [sh*16384, +16KB) = 2 x 8KB K double-buffer.
  // epilogue: reused as 4 x 16KB float partial slots.
  __shared__ __align__(16) char smem[65536];
  __shared__ float Xl[4][2][32];  // [unit][cb][tl]

  const int tid = threadIdx.x;
  const int w = tid >> 6;
  const int lane = tid & 63;
  const int tl = lane & 31;
  const int hi = lane >> 5;
  const int sh = w >> 2;    // s-half stream
  const int u = w & 3;      // t-unit within block
  const int ts = tid & 255; // thread id within stream

  const int bid = blockIdx.x;
  const int vb = (bid & 7) * 32 + (bid >> 3);  // XCD swizzle: 4 bh per XCD
  const int tblk = vb & 7, bh = vb >> 3;
  const int tq0 = tblk * 256 + u * 64;

  const u16* qb = wsQ + (size_t)bh * (SEQ * 64);
  const u16* kb = wsK + (size_t)bh * (SEQ * 64);
  const u16* vstream = wsV + (size_t)bh * 131072 + lane * 8;

  char* Kbuf = smem + sh * 16384;

  // Q fragments: qf[cb][ks] = Q[t=tq0+cb*32+tl][c=16ks+8hi .. +7]
  short8 qf[2][4];
#pragma unroll
  for (int cb = 0; cb < 2; ++cb) {
    const u16* qrow = qb + (size_t)(tq0 + cb * 32 + tl) * 64 + 8 * hi;
#pragma unroll
    for (int ks = 0; ks < 4; ++ks) qf[cb][ks] = *(const short8*)(qrow + 16 * ks);
  }

  f32x16 acc[4];  // [cb*2+ct]
#pragma unroll
  for (int a = 0; a < 4; ++a)
#pragma unroll
    for (int r = 0; r < 16; ++r) acc[a][r] = 0.0f;
  float la0[2] = {0, 0};
  float la1[2] = {0, 0};

  uint4 kg[2];

#define STAGE_LOAD(S)                                                       \
  do {                                                                      \
    _Pragma("unroll")                                                       \
    for (int _it = 0; _it < 2; ++_it) {                                     \
      const int _idx = _it * 256 + ts;                                      \
      const int _row = _idx >> 3, _g = _idx & 7;                            \
      kg[_it] = *(const uint4*)(kb + (size_t)((S) + _row) * 64 + _g * 8);   \
    }                                                                       \
  } while (0)

#define STAGE_WRITE(PBUF)                                                   \
  do {                                                                      \
    char* _kd = Kbuf + (PBUF) * 8192;                                       \
    _Pragma("unroll")                                                       \
    for (int _it = 0; _it < 2; ++_it) {                                     \
      const int _idx = _it * 256 + ts;                                      \
      const int _row = _idx >> 3, _g = _idx & 7;                            \
      *(uint4*)(_kd + _row * 128 + ((_g ^ (_row & 7)) << 4)) = kg[_it];     \
    }                                                                       \
  } while (0)

#define PACK_P(PV16, PF0, PF1)                                                        \
  do {                                                                                \
    u32 _pk[8];                                                                       \
    _Pragma("unroll")                                                                 \
    for (int _q = 0; _q < 8; ++_q) {                                                  \
      const float _lo = PV16[2 * _q], _hi = PV16[2 * _q + 1];                         \
      asm("v_cvt_pk_bf16_f32 %0, %1, %2" : "=v"(_pk[_q]) : "v"(_lo), "v"(_hi));       \
    }                                                                                 \
    asm("v_permlane32_swap_b32 %0, %1" : "+v"(_pk[0]), "+v"(_pk[2]));                 \
    asm("v_permlane32_swap_b32 %0, %1" : "+v"(_pk[1]), "+v"(_pk[3]));                 \
    asm("v_permlane32_swap_b32 %0, %1" : "+v"(_pk[4]), "+v"(_pk[6]));                 \
    asm("v_permlane32_swap_b32 %0, %1" : "+v"(_pk[5]), "+v"(_pk[7]));                 \
    union { u32 u[4]; short8 v; } _f0, _f1;                                           \
    _f0.u[0] = _pk[0]; _f0.u[1] = _pk[1]; _f0.u[2] = _pk[2]; _f0.u[3] = _pk[3];       \
    _f1.u[0] = _pk[4]; _f1.u[1] = _pk[5]; _f1.u[2] = _pk[6]; _f1.u[3] = _pk[7];       \
    PF0 = _f0.v; PF1 = _f1.v;                                                         \
  } while (0)

  // one 32-s subtile: QK -> exp2 -> l -> pack -> PV
#define SUBTILE(SS, JJ)                                                               \
  do {                                                                                \
    const int krow = (SS) * 32 + tl;                                                  \
    short8 kf[4];                                                                     \
    _Pragma("unroll")                                                                 \
    for (int ks = 0; ks < 4; ++ks)                                                    \
      kf[ks] = *(const short8*)(Ks + krow * 128 + (((2 * ks + hi) ^ (krow & 7)) << 4)); \
    f32x16 s0 = {0, 0, 0, 0, 0, 0, 0, 0, 0, 0, 0, 0, 0, 0, 0, 0};                    \
    f32x16 s1 = s0;                                                                   \
    __builtin_amdgcn_s_setprio(1);                                                    \
    _Pragma("unroll")                                                                 \
    for (int ks = 0; ks < 4; ++ks) {                                                  \
      s0 = __builtin_amdgcn_mfma_f32_32x32x16_bf16(kf[ks], qf[0][ks], s0, 0, 0, 0);   \
      s1 = __builtin_amdgcn_mfma_f32_32x32x16_bf16(kf[ks], qf[1][ks], s1, 0, 0, 0);   \
    }                                                                                 \
    __builtin_amdgcn_s_setprio(0);                                                    \
    const u16* vp = vstream + (size_t)(JJ) * 2048;                                    \
    const short8 vf0 = *(const short8*)(vp);                                          \
    const short8 vf1 = *(const short8*)(vp + 512);                                    \
    const short8 vf2 = *(const short8*)(vp + 1024);                                   \
    const short8 vf3 = *(const short8*)(vp + 1536);                                   \
    _Pragma("unroll")                                                                 \
    for (int r = 0; r < 16; ++r) s0[r] = exp2fast(s0[r]);                             \
    _Pragma("unroll")                                                                 \
    for (int r = 0; r < 16; ++r) s1[r] = exp2fast(s1[r]);                             \
    _Pragma("unroll")                                                                 \
    for (int j = 0; j < 2; ++j) {                                                     \
      la0[j] += ((s0[8 * j] + s0[8 * j + 1]) + (s0[8 * j + 2] + s0[8 * j + 3])) +     \
                ((s0[8 * j + 4] + s0[8 * j + 5]) + (s0[8 * j + 6] + s0[8 * j + 7]));  \
      la1[j] += ((s1[8 * j] + s1[8 * j + 1]) + (s1[8 * j + 2] + s1[8 * j + 3])) +     \
                ((s1[8 * j + 4] + s1[8 * j + 5]) + (s1[8 * j + 6] + s1[8 * j + 7]));  \
    }                                                                                 \
    short8 pf00, pf01, pf10, pf11;                                                    \
    PACK_P(s0, pf00, pf01);                                                           \
    PACK_P(s1, pf10, pf11);                                                           \
    __builtin_amdgcn_s_setprio(1);                                                    \
    acc[0] = __builtin_amdgcn_mfma_f32_32x32x16_bf16(vf0, pf00, acc[0], 0, 0, 0);     \
    acc[0] = __builtin_amdgcn_mfma_f32_32x32x16_bf16(vf1, pf01, acc[0], 0, 0, 0);     \
    acc[1] = __builtin_amdgcn_mfma_f32_32x32x16_bf16(vf2, pf00, acc[1], 0, 0, 0);     \
    acc[1] = __builtin_amdgcn_mfma_f32_32x32x16_bf16(vf3, pf01, acc[1], 0, 0, 0);     \
    acc[2] = __builtin_amdgcn_mfma_f32_32x32x16_bf16(vf0, pf10, acc[2], 0, 0, 0);     \
    acc[2] = __builtin_amdgcn_mfma_f32_32x32x16_bf16(vf1, pf11, acc[2], 0, 0, 0);     \
    acc[3] = __builtin_amdgcn_mfma_f32_32x32x16_bf16(vf2, pf10, acc[3], 0, 0, 0);     \
    acc[3] = __builtin_amdgcn_mfma_f32_32x32x16_bf16(vf3, pf11, acc[3], 0, 0, 0);     \
    __builtin_amdgcn_s_setprio(0);                                                    \
  } while (0)

  // prologue: stage tile 0 into buf 0
  STAGE_LOAD(sh * 1024);
  STAGE_WRITE(0);
  __syncthreads();

  for (int i = 0; i < 16; ++i) {
    if (i < 15) STAGE_LOAD(sh * 1024 + (i + 1) * 64);  // T14: load-early

    const char* Ks = Kbuf + (i & 1) * 8192;
    const int jbase = sh * 32 + i * 2;

    SUBTILE(0, jbase);
    // mid-iter STAGE_WRITE: kg long since arrived; ss=1 compute (~2000cyc) covers the
    // ds_write latency so the pre-barrier drain finds them retired.
    if (i < 15) STAGE_WRITE((i + 1) & 1);
    SUBTILE(1, jbase + 1);

    __syncthreads();
  }

  // ---- epilogue: reduce l, 2-stream merge (fixed m => plain sums), store ----
  float l0 = la0[0] + la0[1];
  float l1 = la1[0] + la1[1];
  l0 += __shfl_xor(l0, 32, 64);
  l1 += __shfl_xor(l1, 32, 64);

  float* Xa = (float*)smem + u * 4096;
  if (sh == 1) {
#pragma unroll
    for (int a = 0; a < 4; ++a)
#pragma unroll
      for (int r = 0; r < 16; ++r) Xa[(a * 16 + r) * 64 + lane] = acc[a][r];
    Xl[u][0][tl] = l0;
    Xl[u][1][tl] = l1;
  }
  __syncthreads();
  if (sh == 0) {
    float* ob = out + (size_t)bh * 64 * SEQ;
    const float inv0 = 1.0f / (l0 + Xl[u][0][tl]);
    const float inv1 = 1.0f / (l1 + Xl[u][1][tl]);
#pragma unroll
    for (int r = 0; r < 16; ++r) {
      const int c0 = (r & 3) + 8 * (r >> 2) + 4 * hi;
      const int ta = tq0 + tl, tb2 = tq0 + 32 + tl;
      ob[(size_t)c0 * SEQ + ta] = (acc[0][r] + Xa[(0 * 16 + r) * 64 + lane]) * inv0;
      ob[(size_t)(c0 + 32) * SEQ + ta] = (acc[1][r] + Xa[(1 * 16 + r) * 64 + lane]) * inv0;
      ob[(size_t)c0 * SEQ + tb2] = (acc[2][r] + Xa[(2 * 16 + r) * 64 + lane]) * inv1;
      ob[(size_t)(c0 + 32) * SEQ + tb2] = (acc[3][r] + Xa[(3 * 16 + r) * 64 + lane]) * inv1;
    }
  }
}

extern "C" void kernel_launch(void* const* d_in, const int* in_sizes, int n_in,
                              void* d_out, int out_size, void* d_ws, size_t ws_size,
                              hipStream_t stream) {
  const float* qkv = (const float*)d_in[0];
  float* out = (float*)d_out;
  u16* wsQ = (u16*)d_ws;
  u16* wsK = wsQ + (size_t)32 * SEQ * 64;
  u16* wsV = wsK + (size_t)32 * SEQ * 64;

  prep_all<<<dim3(32, 32, 3), 256, 0, stream>>>(qkv, wsQ, wsK, wsV);
  attn_kernel<<<256, 512, 0, stream>>>(wsQ, wsK, wsV, out);
}